// Round 8
// baseline (10142.839 us; speedup 1.0000x reference)
//
#include <hip/hip_runtime.h>
#include <math.h>

#define N_  2048
#define T_  200
#define D_  16
#define H_  64
#define C2_ 128
#define BM  8
#define NTHR 1024
#define NBLK 256

// X slot: [128][2048] bf16 (h|c transposed) + 4KB guard gap
#define SLOT_USH ((size_t)C2_ * N_ + 2048)

typedef unsigned short ushort_t;
typedef short bf16x8 __attribute__((ext_vector_type(8)));
typedef float f32x4 __attribute__((ext_vector_type(4)));

// ---- f32 weight blob layout (float offsets), all matrices TRANSPOSED [out][in] ----
#define F_HC 0        // W_h_cur^T  [c][k] 64x64
#define F_HP 4096     // W_h_prev^T
#define F_CC 8192     // W_c_cur^T
#define F_CP 12288    // W_c_prev^T
#define F_GH 16384    // W_graph_h^T
#define F_GC 20480    // W_graph_c^T
#define F_R  24576    // R^T [gc][k] 256x64
#define F_K  40960    // K^T [gc][d] 256x16
#define F_B  45056    // bh(64) bc(64) bgh(64) bgc(64) bl(256)
#define F_RS 45568    // rowsum(A_bf16) [2048]
#define FBLOB_F32 47616

__device__ __forceinline__ float sig_(float x) {
    return __fdividef(1.0f, 1.0f + __expf(-x));
}
__device__ __forceinline__ float tanh_(float x) {
    float e = __expf(-2.0f * fabsf(x));
    float t = __fdividef(1.0f - e, 1.0f + e);
    return copysignf(t, x);
}
__device__ __forceinline__ ushort_t f2bf(float f) {
    unsigned u = __float_as_uint(f);
    u = (u + 0x7FFFu + ((u >> 16) & 1u)) >> 16;
    return (ushort_t)u;
}
__device__ __forceinline__ float bf2f(ushort_t u) {
    return __uint_as_float(((unsigned)u) << 16);
}
__device__ __forceinline__ void gload16(const void* g, void* l) {
    __builtin_amdgcn_global_load_lds(
        (const __attribute__((address_space(1))) unsigned int*)g,
        (__attribute__((address_space(3))) unsigned int*)l, 16, 0, 0);
}

// ---- A fp32 -> bf16 + zero barrier counter ----
__global__ __launch_bounds__(256) void convert_A_kernel(
    const float* __restrict__ A, ushort_t* __restrict__ Abf,
    unsigned* __restrict__ cnt)
{
    if (blockIdx.x == 0 && threadIdx.x == 0)
        __hip_atomic_store(cnt, 0u, __ATOMIC_RELAXED, __HIP_MEMORY_SCOPE_AGENT);
    size_t i = ((size_t)blockIdx.x * 256 + threadIdx.x) * 4;
    float4 v = *(const float4*)(A + i);
    ushort4 o;
    o.x = f2bf(v.x); o.y = f2bf(v.y); o.z = f2bf(v.z); o.w = f2bf(v.w);
    *(ushort4*)(Abf + i) = o;
}

// ---- rowsum of bf16 A ----
__global__ __launch_bounds__(256) void rowsum_kernel(
    const ushort_t* __restrict__ Abf, float* __restrict__ fb)
{
    const int row  = blockIdx.x * 4 + (threadIdx.x >> 6);
    const int lane = threadIdx.x & 63;
    float s = 0.f;
    #pragma unroll
    for (int s4 = 0; s4 < 4; s4++) {
        bf16x8 v = *(const bf16x8*)(Abf + (size_t)row * N_ + s4 * 512 + lane * 8);
        #pragma unroll
        for (int i = 0; i < 8; i++) s += bf2f((ushort_t)v[i]);
    }
    #pragma unroll
    for (int off = 32; off >= 1; off >>= 1) s += __shfl_xor(s, off, 64);
    if (lane == 0) fb[F_RS + row] = s;
}

// ---- pack all weights as f32 transposed ----
__global__ __launch_bounds__(256) void convert_Wf_kernel(
    const float* __restrict__ Whc, const float* __restrict__ Whp,
    const float* __restrict__ Wcc, const float* __restrict__ Wcp,
    const float* __restrict__ Wgh, const float* __restrict__ Wgc,
    const float* __restrict__ R,   const float* __restrict__ Kw,
    const float* __restrict__ bh,  const float* __restrict__ bc,
    const float* __restrict__ bgh, const float* __restrict__ bgc,
    const float* __restrict__ bl,
    float* __restrict__ fb)
{
    const int stride = gridDim.x * 256;
    const int gid = blockIdx.x * 256 + threadIdx.x;
    for (int idx = gid; idx < 4096; idx += stride) {   // 64x64 mats, src [k][c]
        int k = idx >> 6, c = idx & 63;
        int dst = c * 64 + k;
        fb[F_HC + dst] = Whc[idx];
        fb[F_HP + dst] = Whp[idx];
        fb[F_CC + dst] = Wcc[idx];
        fb[F_CP + dst] = Wcp[idx];
        fb[F_GH + dst] = Wgh[idx];
        fb[F_GC + dst] = Wgc[idx];
    }
    for (int idx = gid; idx < 16384; idx += stride) {  // R [k][gc]
        int k = idx >> 8, gc = idx & 255;
        fb[F_R + gc * 64 + k] = R[idx];
    }
    for (int idx = gid; idx < 4096; idx += stride) {   // K [d][gc]
        int d = idx >> 8, gc = idx & 255;
        fb[F_K + gc * 16 + d] = Kw[idx];
    }
    if (gid < 64) {
        fb[F_B + gid]       = bh[gid];
        fb[F_B + 64 + gid]  = bc[gid];
        fb[F_B + 128 + gid] = bgh[gid];
        fb[F_B + 192 + gid] = bgc[gid];
    }
    if (gid < 256) fb[F_B + 256 + gid] = bl[gid];
}

// ---- Prologue: slot0 = [h0|c0]^T bf16; h_lstm_0/c_lstm_0 ----
__global__ __launch_bounds__(64) void prologue_kernel(
    const float* __restrict__ xin, const float* __restrict__ h0,
    const float* __restrict__ c0,
    const float* __restrict__ K, const float* __restrict__ R,
    const float* __restrict__ bl,
    ushort_t* __restrict__ Xt, float* __restrict__ hl, float* __restrict__ cl)
{
    const int n = blockIdx.x;
    const int j = threadIdx.x;
    __shared__ float hs[H_], cs[H_], xs[D_];
    hs[j] = h0[n * H_ + j];
    cs[j] = c0[n * H_ + j];
    if (j < D_) xs[j] = xin[(size_t)n * T_ * D_ + j];
    __syncthreads();

    Xt[(size_t)j * N_ + n]        = f2bf(hs[j]);
    Xt[(size_t)(H_ + j) * N_ + n] = f2bf(cs[j]);

    float zi = bl[j], zf = bl[H_ + j], zg = bl[2 * H_ + j], zo = bl[3 * H_ + j];
    for (int d = 0; d < D_; d++) {
        float xv = xs[d];
        zi += xv * K[d * 256 + j];
        zf += xv * K[d * 256 + 64 + j];
        zg += xv * K[d * 256 + 128 + j];
        zo += xv * K[d * 256 + 192 + j];
    }
    for (int k = 0; k < H_; k++) {
        float hv = hs[k];
        zi += hv * R[k * 256 + j];
        zf += hv * R[k * 256 + 64 + j];
        zg += hv * R[k * 256 + 128 + j];
        zo += hv * R[k * 256 + 192 + j];
    }
    float clv = sig_(zf) * cs[j] + sig_(zi) * tanh_(zg);
    float hlv = sig_(zo) * tanh_(clv);
    cl[n * H_ + j] = clv;
    hl[n * H_ + j] = hlv;
}

// ---- Persistent kernel ----
template<bool DEEP>
__global__ __launch_bounds__(NTHR, 4) void persistent_kernel(
    const ushort_t* __restrict__ Abf,
    ushort_t* __restrict__ Xs,
    const float* __restrict__ hl, const float* __restrict__ clm,
    const float* __restrict__ xin,
    const float* __restrict__ FB,
    float* __restrict__ oh, float* __restrict__ oc,
    unsigned* __restrict__ cnt)
{
    __shared__ __align__(16) ushort_t Xw[40960];   // 80 KB: 16 waves x 5 slots x 1KB
    __shared__ __align__(16) float partB[16384];   // 64 KB: 16 planes; Y=partB[0:1024]; Gs=partB[1024:2048]
    __shared__ __align__(16) float HLs[512], CLs[512], HNs[512], CNs[512];
    __shared__ __align__(16) float XSs[128];

    const int tid  = threadIdx.x;
    const int brow = blockIdx.x * BM;
    const int wave = tid >> 6;
    const int lane = tid & 63;
    const int fr   = lane & 15;
    const int kg   = lane >> 4;

    // ---- one-time: stage h_lstm/c_lstm ----
    if (wave == 0) {
        gload16((const char*)(hl + (size_t)brow * H_) + lane * 16, (char*)HLs);
        gload16((const char*)(hl + (size_t)brow * H_) + 1024 + lane * 16, (char*)HLs + 1024);
    }
    if (wave == 1) {
        gload16((const char*)(clm + (size_t)brow * H_) + lane * 16, (char*)CLs);
        gload16((const char*)(clm + (size_t)brow * H_) + 1024 + lane * 16, (char*)CLs + 1024);
    }

    // ---- one-time: A fragments in VGPRs (k-slice = wave*128) ----
    bf16x8 areg[4];
    {
        const ushort_t* ab = Abf + (size_t)(brow + (fr & 7)) * N_ + wave * 128 + kg * 8;
        #pragma unroll
        for (int ks = 0; ks < 4; ks++) areg[ks] = *(const bf16x8*)(ab + ks * 32);
    }

    // ---- one-time: per-thread constants ----
    const int c6 = tid & 63;
    const int r8 = (tid >> 6) & 7;
    const int hi = tid >> 9;
    const float bias_a = FB[F_B + hi * 64 + c6];
    const float bias_g = FB[F_B + 128 + hi * 64 + c6];
    const float rsreg  = FB[F_RS + brow + r8];
    float blr0 = 0.f, blr1 = 0.f, blr2 = 0.f, blr3 = 0.f;
    if (tid < 512) {
        blr0 = FB[F_B + 256 + c6];
        blr1 = FB[F_B + 256 + 64 + c6];
        blr2 = FB[F_B + 256 + 128 + c6];
        blr3 = FB[F_B + 256 + 192 + c6];
    }
    __syncthreads();

    for (int t = 0; t < T_; t++) {
        const ushort_t* Xc = Xs + (size_t)(DEEP ? t : (t & 1)) * SLOT_USH;
        ushort_t*       Xn = Xs + (size_t)(DEEP ? (t + 1) : ((t + 1) & 1)) * SLOT_USH;

        // ---- GEMM: 16 waves, k-slice 128; 5-slot DMA pipeline, 4 in flight ----
        f32x4 acc[8];
        #pragma unroll
        for (int i = 0; i < 8; i++) acc[i] = (f32x4){0.f, 0.f, 0.f, 0.f};
        {
            ushort_t* myslot = &Xw[wave * 2560];
            const int rdoff = (fr * 4 + kg) * 8;   // ush offset of this lane's 16B
            if constexpr (DEEP) {
                const ushort_t* gsrc0 = Xc + (size_t)(lane >> 2) * N_ + wave * 128 + (lane & 3) * 8;
                #define ISSUE(q) gload16(gsrc0 + (size_t)((q) & 7) * 16 * N_ + ((q) >> 3) * 32, \
                                         myslot + ((q) % 5) * 512)
                ISSUE(0); ISSUE(1); ISSUE(2); ISSUE(3);
                #define GSTEP(q, vm) \
                    asm volatile("s_waitcnt vmcnt(" #vm ")" ::: "memory"); \
                    __builtin_amdgcn_sched_barrier(0); \
                    { bf16x8 b = *(const bf16x8*)(myslot + ((q) % 5) * 512 + rdoff); \
                      acc[(q) & 7] = __builtin_amdgcn_mfma_f32_16x16x32_bf16(areg[(q) >> 3], b, acc[(q) & 7], 0, 0, 0); } \
                    if ((q) + 4 < 32) { ISSUE((q) + 4); } \
                    __builtin_amdgcn_sched_barrier(0);
                GSTEP(0,3)  GSTEP(1,3)  GSTEP(2,3)  GSTEP(3,3)
                GSTEP(4,3)  GSTEP(5,3)  GSTEP(6,3)  GSTEP(7,3)
                GSTEP(8,3)  GSTEP(9,3)  GSTEP(10,3) GSTEP(11,3)
                GSTEP(12,3) GSTEP(13,3) GSTEP(14,3) GSTEP(15,3)
                GSTEP(16,3) GSTEP(17,3) GSTEP(18,3) GSTEP(19,3)
                GSTEP(20,3) GSTEP(21,3) GSTEP(22,3) GSTEP(23,3)
                GSTEP(24,3) GSTEP(25,3) GSTEP(26,3) GSTEP(27,3)
                GSTEP(28,3) GSTEP(29,2) GSTEP(30,1) GSTEP(31,0)
                #undef GSTEP
                #undef ISSUE
            } else {
                #pragma unroll
                for (int ks = 0; ks < 4; ks++) {
                    #pragma unroll
                    for (int ct = 0; ct < 8; ct++) {
                        const ushort_t* p = Xc + (size_t)(ct * 16 + fr) * N_
                                          + wave * 128 + ks * 32 + kg * 8;
                        union { unsigned long long q[2]; bf16x8 v; } ub;
                        ub.q[0] = __hip_atomic_load((const unsigned long long*)p,
                                                    __ATOMIC_RELAXED, __HIP_MEMORY_SCOPE_AGENT);
                        ub.q[1] = __hip_atomic_load(((const unsigned long long*)p) + 1,
                                                    __ATOMIC_RELAXED, __HIP_MEMORY_SCOPE_AGENT);
                        acc[ct] = __builtin_amdgcn_mfma_f32_16x16x32_bf16(areg[ks], ub.v, acc[ct], 0, 0, 0);
                    }
                }
            }
            if (kg < 2) {   // rows 8..15 duplicate 0..7 -> discard
                float* pb = &partB[wave * 1024];
                #pragma unroll
                for (int ct = 0; ct < 8; ct++)
                    #pragma unroll
                    for (int r = 0; r < 4; r++)
                        pb[(kg * 4 + r) * C2_ + ct * 16 + fr] = acc[ct][r];
            }
        }
        __syncthreads();

        // ---- reduce 16 planes -> Y (partB[0:1024]); prefetch x_{t+1} ----
        float xr = 0.f;
        if (t + 1 < T_ && tid < 128)
            xr = xin[(size_t)(brow + (tid >> 4)) * (T_ * D_) + (size_t)(t + 1) * D_ + (tid & 15)];
        {
            float s = partB[tid];
            #pragma unroll
            for (int p = 1; p < 16; p++) s += partB[p * 1024 + tid];
            partB[tid] = s;
        }
        __syncthreads();

        // ---- G-fold: Gs = tanh(Y @ Wg + rs*bg); store XSs ----
        if (t + 1 < T_ && tid < 128) XSs[tid] = xr;
        {
            const float* Wf = FB + (hi ? F_GC : F_GH) + c6 * 64;
            const float* Yr = &partB[r8 * C2_ + hi * 64];
            float a = rsreg * bias_g;
            #pragma unroll
            for (int kk = 0; kk < 16; kk++) {
                float4 w = *(const float4*)(Wf + kk * 4);
                a += w.x * Yr[kk*4] + w.y * Yr[kk*4+1] + w.z * Yr[kk*4+2] + w.w * Yr[kk*4+3];
            }
            partB[1024 + r8 * C2_ + hi * 64 + c6] = tanh_(a);
        }
        __syncthreads();

        // ---- epilogue A: h_new (tid<512) / c_new (tid>=512) ----
        {
            const float* W1 = FB + (hi ? F_CC : F_HC) + c6 * 64;
            const float* W2 = FB + (hi ? F_CP : F_HP) + c6 * 64;
            const float* Sv = hi ? &CLs[r8 * 64] : &HLs[r8 * 64];
            const float* Gv = &partB[1024 + r8 * C2_ + hi * 64];
            float a = bias_a;
            #pragma unroll
            for (int kk = 0; kk < 16; kk++) {
                float4 w1 = *(const float4*)(W1 + kk * 4);
                float4 w2 = *(const float4*)(W2 + kk * 4);
                a += w1.x * Sv[kk*4] + w1.y * Sv[kk*4+1] + w1.z * Sv[kk*4+2] + w1.w * Sv[kk*4+3];
                a += w2.x * Gv[kk*4] + w2.y * Gv[kk*4+1] + w2.z * Gv[kk*4+2] + w2.w * Gv[kk*4+3];
            }
            float v = sig_(a);
            (hi ? CNs : HNs)[r8 * 64 + c6] = v;
            float* op = hi ? oc : oh;
            op[(size_t)(brow + r8) * (T_ * H_) + (size_t)t * H_ + c6] = v;
        }

        if (t + 1 == T_) break;
        __syncthreads();

        // ---- exchange store: [h|c]^T bf16, 8B agent-scope stores ----
        if (tid < 256) {
            const int j    = tid >> 1;
            const int half = tid & 1;
            const float* Sv = (j < 64) ? &HNs[j] : &CNs[j - 64];
            unsigned long long v =
                  (unsigned long long)f2bf(Sv[(half * 4 + 0) * 64])
                | ((unsigned long long)f2bf(Sv[(half * 4 + 1) * 64]) << 16)
                | ((unsigned long long)f2bf(Sv[(half * 4 + 2) * 64]) << 32)
                | ((unsigned long long)f2bf(Sv[(half * 4 + 3) * 64]) << 48);
            __hip_atomic_store((unsigned long long*)(Xn + (size_t)j * N_ + brow + half * 4),
                               v, __ATOMIC_RELAXED, __HIP_MEMORY_SCOPE_AGENT);
        }
        __syncthreads();   // drains stores (vmcnt 0 before s_barrier)

        // ---- arrive (non-blocking), then hide barrier latency under epiC ----
        if (tid == 0)
            __hip_atomic_fetch_add(cnt, 1u, __ATOMIC_RELAXED, __HIP_MEMORY_SCOPE_AGENT);

        // ---- epilogue C: LSTM gates for t+1 (tid<512) -> HLs/CLs ----
        if (tid < 512) {
            float z0 = blr0, z1 = blr1, z2 = blr2, z3 = blr3;
            const float* xb = &XSs[r8 * 16];
            const float* hb = &HNs[r8 * 64];
            #pragma unroll
            for (int dd = 0; dd < 4; dd++) {
                float4 w0 = *(const float4*)(FB + F_K + (0 * 64 + c6) * 16 + dd * 4);
                float4 w1 = *(const float4*)(FB + F_K + (1 * 64 + c6) * 16 + dd * 4);
                float4 w2 = *(const float4*)(FB + F_K + (2 * 64 + c6) * 16 + dd * 4);
                float4 w3 = *(const float4*)(FB + F_K + (3 * 64 + c6) * 16 + dd * 4);
                float x0 = xb[dd*4], x1 = xb[dd*4+1], x2 = xb[dd*4+2], x3 = xb[dd*4+3];
                z0 += w0.x*x0 + w0.y*x1 + w0.z*x2 + w0.w*x3;
                z1 += w1.x*x0 + w1.y*x1 + w1.z*x2 + w1.w*x3;
                z2 += w2.x*x0 + w2.y*x1 + w2.z*x2 + w2.w*x3;
                z3 += w3.x*x0 + w3.y*x1 + w3.z*x2 + w3.w*x3;
            }
            #pragma unroll
            for (int kk = 0; kk < 16; kk++) {
                float4 w0 = *(const float4*)(FB + F_R + (0 * 64 + c6) * 64 + kk * 4);
                float4 w1 = *(const float4*)(FB + F_R + (1 * 64 + c6) * 64 + kk * 4);
                float4 w2 = *(const float4*)(FB + F_R + (2 * 64 + c6) * 64 + kk * 4);
                float4 w3 = *(const float4*)(FB + F_R + (3 * 64 + c6) * 64 + kk * 4);
                float h0v = hb[kk*4], h1v = hb[kk*4+1], h2v = hb[kk*4+2], h3v = hb[kk*4+3];
                z0 += w0.x*h0v + w0.y*h1v + w0.z*h2v + w0.w*h3v;
                z1 += w1.x*h0v + w1.y*h1v + w1.z*h2v + w1.w*h3v;
                z2 += w2.x*h0v + w2.y*h1v + w2.z*h2v + w2.w*h3v;
                z3 += w3.x*h0v + w3.y*h1v + w3.z*h2v + w3.w*h3v;
            }
            float clv = sig_(z1) * CNs[r8 * 64 + c6] + sig_(z0) * tanh_(z2);
            float hlv = sig_(z3) * tanh_(clv);
            CLs[r8 * 64 + c6] = clv;
            HLs[r8 * 64 + c6] = hlv;
        }

        // ---- poll barrier completion ----
        if (tid == 0) {
            const unsigned target = (unsigned)NBLK * (unsigned)(t + 1);
            while (__hip_atomic_load(cnt, __ATOMIC_RELAXED, __HIP_MEMORY_SCOPE_AGENT) < target)
                __builtin_amdgcn_s_sleep(2);
        }
        __syncthreads();
        asm volatile("" ::: "memory");
    }
}

extern "C" void kernel_launch(void* const* d_in, const int* in_sizes, int n_in,
                              void* d_out, int out_size, void* d_ws, size_t ws_size,
                              hipStream_t stream) {
    const float* xin = (const float*)d_in[0];
    const float* h0  = (const float*)d_in[1];
    const float* c0  = (const float*)d_in[2];
    const float* A   = (const float*)d_in[3];
    const float* Wgh = (const float*)d_in[4];
    const float* bgh = (const float*)d_in[5];
    const float* Wgc = (const float*)d_in[6];
    const float* bgc = (const float*)d_in[7];
    const float* Whc = (const float*)d_in[8];
    const float* Whp = (const float*)d_in[9];
    const float* bh  = (const float*)d_in[10];
    const float* Wcc = (const float*)d_in[11];
    const float* Wcp = (const float*)d_in[12];
    const float* bc  = (const float*)d_in[13];
    const float* K   = (const float*)d_in[14];
    const float* R   = (const float*)d_in[15];
    const float* bl  = (const float*)d_in[16];

    const size_t fixed = (size_t)N_ * N_ * 2
                       + (size_t)N_ * H_ * 4 * 2
                       + (size_t)FBLOB_F32 * 4 + 256;
    const size_t slot_bytes = SLOT_USH * 2;
    const bool deep = ws_size >= fixed + (size_t)(T_ + 1) * slot_bytes;
    const int nslots = deep ? (T_ + 1) : 2;

    char* w = (char*)d_ws;
    ushort_t* Abf  = (ushort_t*)w;  w += (size_t)N_ * N_ * 2;
    ushort_t* Xs   = (ushort_t*)w;  w += (size_t)nslots * slot_bytes;
    float* hl      = (float*)w;     w += (size_t)N_ * H_ * 4;
    float* cl      = (float*)w;     w += (size_t)N_ * H_ * 4;
    float* fblob   = (float*)w;     w += (size_t)FBLOB_F32 * 4;
    unsigned* cnt  = (unsigned*)w;  w += 256;

    float* oh = (float*)d_out;
    float* oc = oh + (size_t)N_ * T_ * H_;

    convert_A_kernel<<<(N_ * N_) / (256 * 4), 256, 0, stream>>>(A, Abf, cnt);
    rowsum_kernel<<<N_ / 4, 256, 0, stream>>>(Abf, fblob);
    convert_Wf_kernel<<<16, 256, 0, stream>>>(Whc, Whp, Wcc, Wcp, Wgh, Wgc, R, K,
                                              bh, bc, bgh, bgc, bl, fblob);
    prologue_kernel<<<N_, 64, 0, stream>>>(xin, h0, c0, K, R, bl, Xs, hl, cl);

    void* args[] = { (void*)&Abf, (void*)&Xs, (void*)&hl, (void*)&cl,
                     (void*)&xin, (void*)&fblob, (void*)&oh, (void*)&oc, (void*)&cnt };
    if (deep)
        hipLaunchCooperativeKernel((const void*)persistent_kernel<true>,
                                   dim3(NBLK), dim3(NTHR), args, 0, stream);
    else
        hipLaunchCooperativeKernel((const void*)persistent_kernel<false>,
                                   dim3(NBLK), dim3(NTHR), args, 0, stream);
}